// Round 8
// baseline (211.931 us; speedup 1.0000x reference)
//
#include <hip/hip_runtime.h>

#define BB 32
#define TT 128
#define PP 512
#define DD 300
#define KT 10      // K chunks of 32 (KP = 320 = 300 data + bias slot + zeros)
#define NR 13      // retained cols per pattern (tm[13] is dead)
#define NN 6656    // P * NR (GEMM n-extent, row-major C stride)
#define AT 256     // A tiles (4096/16)
#define BT 416     // B tiles (6656/16)
#define NEG -1e30f

typedef _Float16 half8 __attribute__((ext_vector_type(8)));
typedef float floatx4 __attribute__((ext_vector_type(4)));

__device__ __forceinline__ void async_load16(const void* g, void* l) {
    __builtin_amdgcn_global_load_lds(
        (const __attribute__((address_space(1))) void*)g,
        (__attribute__((address_space(3))) void*)l, 16, 0, 0);
}

__device__ __forceinline__ floatx4 mfma16(half8 a, half8 b, floatx4 c) {
    return __builtin_amdgcn_mfma_f32_16x16x32_f16(a, b, c, 0, 0, 0);
}

// ---------------------------------------------------------------------------
// Pack into MFMA-fragment-blocked layout + error-free f16 Dekker split.
// lo stored as r*2^6 (the 2^-12 is absorbed by multiplying the PARTNER hi
// operand by 2^-6 in-register inside the GEMM -> single accumulator).
// Chunk (tile16, kt32) = 1KB: half idx = lane*8+i, row = tile*16+(lane&15),
// k = kt*32+(lane>>4)*8+i. K-slot 300 carries bias (A side exact 1.0).
// ---------------------------------------------------------------------------
__global__ __launch_bounds__(256) void pack_kernel(
    const int* __restrict__ tokens, const float* __restrict__ emb,
    const float* __restrict__ diags, const float* __restrict__ bias,
    _Float16* __restrict__ AhP, _Float16* __restrict__ AlP,
    _Float16* __restrict__ BhP, _Float16* __restrict__ BlP)
{
    const int idx = blockIdx.x * 256 + threadIdx.x;
    if (idx >= (AT + BT) * KT * 64) return;
    const int chunk = idx >> 6;
    const int ln = idx & 63;

    const float* src;
    float kslot;
    _Float16 *dh, *dl;
    int kt;
    if (chunk < AT * KT) {
        const int mt = chunk / KT; kt = chunk - mt * KT;
        const int m = mt * 16 + (ln & 15);
        src = emb + (size_t)tokens[m] * DD;
        kslot = 1.0f;
        dh = AhP + (size_t)chunk * 512 + ln * 8;
        dl = AlP + (size_t)chunk * 512 + ln * 8;
    } else {
        const int c2 = chunk - AT * KT;
        const int nt = c2 / KT; kt = c2 - nt * KT;
        const int n = nt * 16 + (ln & 15);
        const int p = n / NR;
        const int srow = p * 14 + (n - p * NR);
        src = diags + (size_t)srow * DD;
        kslot = bias[srow];
        dh = BhP + (size_t)c2 * 512 + ln * 8;
        dl = BlP + (size_t)c2 * 512 + ln * 8;
    }

    const int k0 = kt * 32 + (ln >> 4) * 8;
    float v[8];
    if (k0 + 8 <= DD) {
        float4 a = *(const float4*)(src + k0);
        float4 b = *(const float4*)(src + k0 + 4);
        v[0] = a.x; v[1] = a.y; v[2] = a.z; v[3] = a.w;
        v[4] = b.x; v[5] = b.y; v[6] = b.z; v[7] = b.w;
    } else {
        #pragma unroll
        for (int i = 0; i < 8; ++i) {
            const int k = k0 + i;
            v[i] = (k < DD) ? src[k] : (k == DD ? kslot : 0.f);
        }
    }
    half8 h, l;
    #pragma unroll
    for (int i = 0; i < 8; ++i) {
        h[i] = (_Float16)v[i];
        l[i] = (_Float16)((v[i] - (float)h[i]) * 64.f);   // r * 2^6
    }
    *(half8*)dh = h;
    *(half8*)dl = l;
}

// ---------------------------------------------------------------------------
// GEMM: C[m][n] = sum_k A[m][k]*B[n][k] (bias folded into k=300).
// Single-accumulator 3-product Dekker: acc += ah*bh + (ra*2^6)*(bh*2^-6)
// + (ah*2^-6)*(rb*2^6). A-hi direct global->VGPR (double-buffered,
// L2-resident via XCD swizzle); A-lo + B-hi + B-lo through LDS (frag layout
// via global_load_lds, double-buffered, conflict-free linear reads).
// 128x128 tile, 4 waves 2x2. 3 blocks/CU (64 accum + ~100 arch VGPRs,
// 48 KB LDS). XCD swizzle: bid&7 -> fixed 4-m-block band per XCD.
// ---------------------------------------------------------------------------
__global__ __launch_bounds__(256, 3) void gemm_kernel(
    const _Float16* __restrict__ AhP, const _Float16* __restrict__ AlP,
    const _Float16* __restrict__ BhP, const _Float16* __restrict__ BlP,
    float* __restrict__ C)
{
    __shared__ __align__(16) _Float16 AsL[2][8 * 512];
    __shared__ __align__(16) _Float16 BsH[2][8 * 512];
    __shared__ __align__(16) _Float16 BsL[2][8 * 512];

    const int tid = threadIdx.x;
    const int w = tid >> 6, ln = tid & 63;
    // XCD-aware swizzle: xcd = bid&7 works m-blocks [xcd*4, xcd*4+4)
    const int bid = blockIdx.x;
    const int m0t = ((bid & 7) * 4 + ((bid >> 3) & 3)) * 8;   // m-tile base
    const int n0t = (bid >> 5) * 8;                            // n-tile base
    const int wm = w & 1, wn = w >> 1;

    floatx4 acc[4][4];
    #pragma unroll
    for (int i = 0; i < 4; ++i)
        #pragma unroll
        for (int j = 0; j < 4; ++j) acc[i][j] = (floatx4){0.f, 0.f, 0.f, 0.f};

    half8 ah[2][4];

    auto loadAh = [&](int kt, int pb) {
        #pragma unroll
        for (int i = 0; i < 4; ++i) {
            const size_t ch = ((size_t)(m0t + wm * 4 + i) * KT + kt) * 512 + ln * 8;
            ah[pb][i] = *(const half8*)(AhP + ch);
        }
    };
    auto stage = [&](int kt, int buf) {
        #pragma unroll
        for (int s = 0; s < 2; ++s) {
            const int nt = w + s * 4;   // wave w stages tiles {w, w+4}
            const size_t cb_ = ((size_t)(n0t + nt) * KT + kt) * 512 + ln * 8;
            const size_t ca_ = ((size_t)(m0t + nt) * KT + kt) * 512 + ln * 8;
            async_load16(BhP + cb_, &BsH[buf][nt * 512]);
            async_load16(BlP + cb_, &BsL[buf][nt * 512]);
            async_load16(AlP + ca_, &AsL[buf][nt * 512]);
        }
    };

    stage(0, 0);
    loadAh(0, 0);
    __syncthreads();

    const _Float16 s6 = (_Float16)0.015625f;   // 2^-6, exact

    #pragma unroll
    for (int kt = 0; kt < KT; ++kt) {
        const int cb = kt & 1, nb = cb ^ 1;
        if (kt + 1 < KT) {
            loadAh(kt + 1, nb);
            stage(kt + 1, nb);
        }
        half8 alr[4], ahs[4];
        #pragma unroll
        for (int i = 0; i < 4; ++i) {
            alr[i] = *(const half8*)&AsL[cb][(wm * 4 + i) * 512 + ln * 8];
            ahs[i] = ah[cb][i] * s6;
        }
        #pragma unroll
        for (int j = 0; j < 4; ++j) {
            const half8 bh = *(const half8*)&BsH[cb][(wn * 4 + j) * 512 + ln * 8];
            const half8 bl = *(const half8*)&BsL[cb][(wn * 4 + j) * 512 + ln * 8];
            const half8 bhs = bh * s6;
            #pragma unroll
            for (int i = 0; i < 4; ++i) {
                acc[i][j] = mfma16(ah[cb][i], bh, acc[i][j]);
                acc[i][j] = mfma16(alr[i], bhs, acc[i][j]);
                acc[i][j] = mfma16(ahs[i], bl, acc[i][j]);
            }
        }
        __syncthreads();
    }

    // epilogue: C/D layout col(n)=lane&15, row(m)=(lane>>4)*4+reg
    #pragma unroll
    for (int j = 0; j < 4; ++j) {
        const int n = (n0t + wn * 4 + j) * 16 + (ln & 15);
        #pragma unroll
        for (int i = 0; i < 4; ++i) {
            const int mb = (m0t + wm * 4 + i) * 16 + (ln >> 4) * 4;
            #pragma unroll
            for (int r = 0; r < 4; ++r)
                C[(size_t)(mb + r) * NN + n] = acc[i][j][r];
        }
    }
}

// ---------------------------------------------------------------------------
// Chunk-parallel max-sum scan (max-plus affine composition), as R7.
// Block = 4 chunk-waves x 64 patterns; maps combined through 64KB LDS.
// ---------------------------------------------------------------------------
__global__ __launch_bounds__(256, 2) void scan_kernel(
    const float* __restrict__ C,
    const float* __restrict__ epsilons,
    const int* __restrict__ doc_lens,
    float* __restrict__ scores)
{
    __shared__ float smaps[64][256];   // [component][tid] = 64 KiB

    const int tid = threadIdx.x;
    const int ln = tid & 63;
    const int ch = tid >> 6;
    const int b = blockIdx.x, pg = blockIdx.y;
    const int p = pg * 64 + ln;
    const int dl = doc_lens[b];
    const bool end5 = (p < 256);

    float e[6];
    #pragma unroll
    for (int i = 0; i < 6; ++i) e[i] = epsilons[p * 6 + i];

    float A[7][7], c[7], S[7], s0;
    #pragma unroll
    for (int i = 0; i < 7; ++i) {
        #pragma unroll
        for (int j = 0; j < 7; ++j) A[i][j] = (i == j) ? 0.f : NEG;
        c[i] = NEG; S[i] = NEG;
    }
    s0 = NEG;

    const float* base = C + (size_t)(b * 128 + ch * 32) * NN + p * NR;

    float vb[2][NR];
    {
        #pragma unroll
        for (int i = 0; i < NR; ++i) vb[0][i] = base[i];
    }

    #pragma unroll
    for (int s = 0; s < 32; ++s) {
        if (s + 1 < 32) {
            const float* src = base + (size_t)(s + 1) * NN;
            #pragma unroll
            for (int i = 0; i < NR; ++i) vb[(s + 1) & 1][i] = src[i];
        }
        const float* v = vb[s & 1];
        #pragma unroll
        for (int l = 6; l >= 1; --l) {
            const float el = e[l - 1];
            #pragma unroll
            for (int j = 0; j < 7; ++j) A[l][j] = fmaxf(A[l][j], A[l - 1][j] + el);
            c[l] = fmaxf(c[l], c[l - 1] + el);
        }
        #pragma unroll
        for (int l = 6; l >= 1; --l) {
            const float wl = v[7 + l - 1], vl = v[l];
            #pragma unroll
            for (int j = 0; j < 7; ++j)
                A[l][j] = fmaxf(A[l - 1][j] + wl, A[l][j] + vl);
            c[l] = fmaxf(c[l - 1] + wl, c[l] + vl);
        }
        #pragma unroll
        for (int j = 0; j < 7; ++j) A[0][j] += v[0];
        c[0] = fmaxf(c[0] + v[0], 0.f);
        const int t = ch * 32 + s;
        if (t < dl) {
            #pragma unroll
            for (int j = 0; j < 7; ++j)
                S[j] = fmaxf(S[j], end5 ? A[5][j] : A[6][j]);
            s0 = fmaxf(s0, end5 ? c[5] : c[6]);
        }
    }

    #pragma unroll
    for (int i = 0; i < 7; ++i) {
        #pragma unroll
        for (int j = 0; j < 7; ++j) smaps[i * 7 + j][tid] = A[i][j];
        smaps[49 + i][tid] = c[i];
        smaps[56 + i][tid] = S[i];
    }
    smaps[63][tid] = s0;
    __syncthreads();

    if (ch == 0) {
        float h[7];
        h[0] = 0.f;
        #pragma unroll
        for (int i = 1; i < 7; ++i) h[i] = NEG;
        float sc = NEG;
        #pragma unroll
        for (int cc = 0; cc < 4; ++cc) {
            const int src = cc * 64 + ln;
            float m = smaps[63][src];
            #pragma unroll
            for (int j = 0; j < 7; ++j) m = fmaxf(m, smaps[56 + j][src] + h[j]);
            sc = fmaxf(sc, m);
            float nh[7];
            #pragma unroll
            for (int i = 0; i < 7; ++i) {
                float x = smaps[49 + i][src];
                #pragma unroll
                for (int j = 0; j < 7; ++j)
                    x = fmaxf(x, smaps[i * 7 + j][src] + h[j]);
                nh[i] = x;
            }
            #pragma unroll
            for (int i = 0; i < 7; ++i) h[i] = nh[i];
        }
        scores[p * BB + b] = sc;
    }
}

// ---------------------------------------------------------------------------
// BatchNorm (batch stats) + sign(relu) + final linear. One block.
// ---------------------------------------------------------------------------
__global__ __launch_bounds__(512) void finalize_kernel(
    const float* __restrict__ scores,
    const float* __restrict__ bn_w,
    const float* __restrict__ bn_b,
    const float* __restrict__ fw,
    const float* __restrict__ fb,
    float* __restrict__ out)
{
    __shared__ float acc[64];
    const int p = threadIdx.x;
    if (p < 64) acc[p] = 0.f;
    __syncthreads();

    float x[32];
    const float4* sp = (const float4*)(scores + p * 32);
    #pragma unroll
    for (int i = 0; i < 8; ++i) ((float4*)x)[i] = sp[i];

    float mean = 0.f;
    #pragma unroll
    for (int i = 0; i < 32; ++i) mean += x[i];
    mean *= (1.f / 32.f);
    float var = 0.f;
    #pragma unroll
    for (int i = 0; i < 32; ++i) { const float d = x[i] - mean; var = fmaf(d, d, var); }
    var *= (1.f / 32.f);

    const float scale = (1.f / sqrtf(var + 1e-5f)) * bn_w[p];
    const float shift = bn_b[p];
    const float w0 = fw[p], w1 = fw[PP + p];

    for (int b = 0; b < 32; ++b) {
        const float v = (x[b] - mean) * scale + shift;
        const bool bin = v > 0.f;
        float v0 = bin ? w0 : 0.f;
        float v1 = bin ? w1 : 0.f;
        #pragma unroll
        for (int o = 32; o; o >>= 1) {
            v0 += __shfl_xor(v0, o);
            v1 += __shfl_xor(v1, o);
        }
        if ((threadIdx.x & 63) == 0) {
            atomicAdd(&acc[b * 2 + 0], v0);
            atomicAdd(&acc[b * 2 + 1], v1);
        }
    }
    __syncthreads();
    if (p < 64) out[p] = acc[p] + fb[p & 1];
}

// ---------------------------------------------------------------------------
extern "C" void kernel_launch(void* const* d_in, const int* in_sizes, int n_in,
                              void* d_out, int out_size, void* d_ws, size_t ws_size,
                              hipStream_t stream) {
    const int*   tokens   = (const int*)d_in[0];
    const int*   doc_lens = (const int*)d_in[1];
    const float* emb      = (const float*)d_in[2];
    const float* diags    = (const float*)d_in[3];
    const float* bias     = (const float*)d_in[4];
    const float* eps      = (const float*)d_in[5];
    const float* bnw      = (const float*)d_in[6];
    const float* bnb      = (const float*)d_in[7];
    const float* fw       = (const float*)d_in[8];
    const float* fb       = (const float*)d_in[9];
    float* out = (float*)d_out;

    float* ts     = (float*)d_ws;                    // [4096][6656] = 109 MB
    float* scores = ts + (size_t)4096 * NN;          // [512][32]
    _Float16* AhP = (_Float16*)(scores + PP * BB);   // frag-blocked packs
    _Float16* AlP = AhP + (size_t)AT * KT * 512;
    _Float16* BhP = AlP + (size_t)AT * KT * 512;
    _Float16* BlP = BhP + (size_t)BT * KT * 512;

    pack_kernel<<<(AT + BT) * KT * 64 / 256, 256, 0, stream>>>(
        tokens, emb, diags, bias, AhP, AlP, BhP, BlP);
    gemm_kernel<<<dim3(BT / 8 * AT / 8), 256, 0, stream>>>(AhP, AlP, BhP, BlP, ts);
    scan_kernel<<<dim3(BB, PP / 64), 256, 0, stream>>>(ts, eps, doc_lens, scores);
    finalize_kernel<<<1, 512, 0, stream>>>(scores, bnw, bnb, fw, fb, out);
}